// Round 2
// baseline (7437.730 us; speedup 1.0000x reference)
//
#include <hip/hip_runtime.h>
#include <hip/hip_fp16.h>

// ---------------------------------------------------------------------------
// 2-layer bidirectional tanh RNN, B=32, T=512, E=256, H=512.
// Strategy:
//   1. prep:   fp32->fp16 conversions (+ xs transpose to [T,B,E], bias sums)
//   2. gemm:   pre[d][t*32+b][j] = X @ W_ih[d]^T + bias   (fp16 MFMA, fp16 out)
//   3. rnn:    512 sequential steps; 16 blocks per direction, each owns a
//              32-wide j-slice of W_hh held in VGPRs as MFMA B-fragments.
//              h state exchanged via double-buffered global fp16 buffer +
//              per-block flag barrier (device-scope atomics, __threadfence).
//   4. repeat gemm+rnn for layer 1 (input = concat(hf,hb) staged fp16).
// ---------------------------------------------------------------------------

#define T_ 512
#define B_ 32
#define E_ 256
#define H_ 512

using half8 = _Float16 __attribute__((ext_vector_type(8)));
using f32x4 = float __attribute__((ext_vector_type(4)));

// workspace layout (bytes)
static constexpr size_t OFF_PRE   = 0;                         // f16 [2][16384][512]  32 MB (reused by both layers)
static constexpr size_t OFF_XH1   = 32ull << 20;               // f16 [16384][1024]    32 MB
static constexpr size_t OFF_X0H   = 64ull << 20;               // f16 [16384][256]      8 MB
static constexpr size_t OFF_W0H   = 72ull << 20;               // f16 [2][512][256]   0.5 MB
static constexpr size_t OFF_W1H   = OFF_W0H + (512ull << 10);  // f16 [2][512][1024]    2 MB
static constexpr size_t OFF_WHH   = OFF_W1H + (2ull << 20);    // f16 [2][2][512][512]  2 MB (layer,dir)
static constexpr size_t OFF_BS    = OFF_WHH + (2ull << 20);    // f32 [2][2][512]       8 KB
static constexpr size_t OFF_HBUF  = OFF_BS + (8ull << 10);     // f16 [2][2][2][32][512] 256 KB (layer,dir,phase)
static constexpr size_t OFF_FLAGS = OFF_HBUF + (256ull << 10); // int [2][2][16] in 4 KB
static constexpr size_t ZERO_SIZE = (256ull << 10) + 4096;     // hbuf + flags

// ---------------------------------------------------------------------------
__global__ void prep_kernel(const float* __restrict__ xs,
                            const float* __restrict__ wih0,
                            const float* __restrict__ whh0,
                            const float* __restrict__ b0,
                            const float* __restrict__ wih1,
                            const float* __restrict__ whh1,
                            const float* __restrict__ b1,
                            _Float16* __restrict__ x0h,
                            _Float16* __restrict__ w0h,
                            _Float16* __restrict__ w1h,
                            _Float16* __restrict__ whh,
                            float* __restrict__ bsum)
{
    const int N0 = T_ * B_ * E_;   // 4194304  xs transpose+convert
    const int N1 = 2 * H_ * E_;    // 262144   w_ih0
    const int N2 = 2 * H_ * 2*H_;  // 1048576  w_ih1
    const int N3 = 2 * H_ * H_;    // 524288   w_hh per layer
    const int total = N0 + N1 + N2 + 2 * N3 + 2048;
    for (int idx = blockIdx.x * blockDim.x + threadIdx.x; idx < total;
         idx += gridDim.x * blockDim.x) {
        int i = idx;
        if (i < N0) {
            // x0h[(t*32+b)*256 + e] = xs[(b*512+t)*256 + e]
            int t = i >> 13;
            int r = i & 8191;
            int b = r >> 8;
            int e = r & 255;
            x0h[i] = (_Float16)xs[((size_t)(b << 9) + t) * 256 + e];
        } else if ((i -= N0) < N1) {
            w0h[i] = (_Float16)wih0[i];
        } else if ((i -= N1) < N2) {
            w1h[i] = (_Float16)wih1[i];
        } else if ((i -= N2) < N3) {
            whh[i] = (_Float16)whh0[i];
        } else if ((i -= N3) < N3) {
            whh[N3 + i] = (_Float16)whh1[i];
        } else {
            i -= N3;               // 0..2047: [layer][dir][512]
            int layer = i >> 10;
            int r = i & 1023;
            int d = r >> 9;
            int j = r & 511;
            const float* bb = layer ? b1 : b0;
            bsum[i] = bb[d * 1024 + j] + bb[d * 1024 + 512 + j];
        }
    }
}

// ---------------------------------------------------------------------------
// out[d][m][n] (f16) = sum_k X[m][k] * W[d][n][k] + bias[d][n]
// M = 16384 (= t*32+b), N = 512 per dir, K in {256, 1024}.
__global__ __launch_bounds__(256, 2)
void gemm_kernel(const _Float16* __restrict__ X,
                 const _Float16* __restrict__ W,
                 const float* __restrict__ bias,
                 _Float16* __restrict__ out, int K)
{
    __shared__ _Float16 Ash[64][72];   // +8 pad: 2-way-max bank aliasing
    __shared__ _Float16 Bsh[64][72];
    const int m0 = blockIdx.x * 64, n0 = blockIdx.y * 64, d = blockIdx.z;
    const _Float16* Wd = W + (size_t)d * 512 * K;
    const int tid = threadIdx.x;
    const int l = tid & 63, w = tid >> 6;
    const int wm = w & 1, wn = w >> 1;          // wave tile = [32m x 32n]
    const int lm = l & 15, q = l >> 4;
    f32x4 c[2][2] = {};
    for (int kk = 0; kk < K; kk += 64) {
        for (int ci = tid; ci < 512; ci += 256) {
            int row = ci >> 3, col = (ci & 7) * 8;
            *(half8*)&Ash[row][col] =
                *(const half8*)&X[(size_t)(m0 + row) * K + kk + col];
            *(half8*)&Bsh[row][col] =
                *(const half8*)&Wd[(size_t)(n0 + row) * K + kk + col];
        }
        __syncthreads();
        for (int kt = 0; kt < 2; ++kt) {
            const int kof = kt * 32 + q * 8;
            half8 a0 = *(const half8*)&Ash[wm * 32 + lm][kof];
            half8 a1 = *(const half8*)&Ash[wm * 32 + 16 + lm][kof];
            half8 b0f = *(const half8*)&Bsh[wn * 32 + lm][kof];
            half8 b1f = *(const half8*)&Bsh[wn * 32 + 16 + lm][kof];
            c[0][0] = __builtin_amdgcn_mfma_f32_16x16x32_f16(a0, b0f, c[0][0], 0, 0, 0);
            c[0][1] = __builtin_amdgcn_mfma_f32_16x16x32_f16(a0, b1f, c[0][1], 0, 0, 0);
            c[1][0] = __builtin_amdgcn_mfma_f32_16x16x32_f16(a1, b0f, c[1][0], 0, 0, 0);
            c[1][1] = __builtin_amdgcn_mfma_f32_16x16x32_f16(a1, b1f, c[1][1], 0, 0, 0);
        }
        __syncthreads();
    }
    _Float16* outd = out + (size_t)d * 16384 * 512;
    for (int mi = 0; mi < 2; ++mi)
        for (int ni = 0; ni < 2; ++ni) {
            int col = n0 + wn * 32 + ni * 16 + lm;
            float bv = bias[d * 512 + col];
            for (int r = 0; r < 4; ++r) {
                int rowm = m0 + wm * 32 + mi * 16 + q * 4 + r;
                outd[(size_t)rowm * 512 + col] = (_Float16)(c[mi][ni][r] + bv);
            }
        }
}

// ---------------------------------------------------------------------------
// One direction = 16 blocks; block g owns j-slice [g*32, g*32+32).
// W_hh slice lives in VGPRs as B-fragments (loaded once). h state in global,
// double-buffered by step parity, flag barrier per step.
__global__ __launch_bounds__(128, 1)
void rnn_kernel(const _Float16* __restrict__ pre,   // [2][16384][512] f16
                const _Float16* __restrict__ whh,   // this layer: [2][512][512] f16
                _Float16* __restrict__ hbuf,        // [2 dir][2 phase][32][512] f16
                int* __restrict__ flags,            // [2 dir][16]
                _Float16* __restrict__ xh1,         // layer0 out: [16384][1024] f16
                float* __restrict__ dout,           // final output buffer
                int layer)
{
    const int gid = blockIdx.x;
    const int d = gid >> 4, g = gid & 15;
    const int tid = threadIdx.x, l = tid & 63, mt = tid >> 6;
    const int lm = l & 15, q = l >> 4;

    // Preload B-fragments: lane holds W[j = n][k], n = lane&15, k = q*8+e.
    half8 Bf[2][16];
    for (int nt = 0; nt < 2; ++nt) {
        const _Float16* wrow = whh + ((size_t)d * 512 + g * 32 + nt * 16 + lm) * 512;
        for (int kt = 0; kt < 16; ++kt)
            Bf[nt][kt] = *(const half8*)&wrow[kt * 32 + q * 8];
    }

    const int bq = mt * 16 + q * 4;   // C/D row base (b), + reg r
    const int bA = mt * 16 + lm;      // A-fragment row (b)
    _Float16* hb = hbuf + (size_t)d * 2 * B_ * H_;
    int* fl = flags + d * 16;

    for (int s = 0; s < T_; ++s) {
        const int t = d ? (T_ - 1 - s) : s;
        const _Float16* hsrc = hb + (size_t)(s & 1) * B_ * H_;
        _Float16* hdst = hb + (size_t)((s + 1) & 1) * B_ * H_;

        // A-fragments of h(s): lane holds h[b = mt*16 + (l&15)][k = q*8+e]
        half8 A[16];
        const _Float16* hrow = hsrc + (size_t)bA * H_ + q * 8;
        for (int kt = 0; kt < 16; ++kt)
            A[kt] = *(const half8*)&hrow[kt * 32];

        // C init = pre[d][t][b][j]
        const _Float16* prow = pre + ((size_t)d * 16384 + (size_t)t * B_) * 512;
        f32x4 c[2];
        for (int nt = 0; nt < 2; ++nt) {
            const int j = g * 32 + nt * 16 + lm;
            for (int r = 0; r < 4; ++r)
                c[nt][r] = (float)prow[(size_t)(bq + r) * 512 + j];
        }

        for (int kt = 0; kt < 16; ++kt) {
            c[0] = __builtin_amdgcn_mfma_f32_16x16x32_f16(A[kt], Bf[0][kt], c[0], 0, 0, 0);
            c[1] = __builtin_amdgcn_mfma_f32_16x16x32_f16(A[kt], Bf[1][kt], c[1], 0, 0, 0);
        }

        // tanh + publish
        for (int nt = 0; nt < 2; ++nt) {
            const int j = g * 32 + nt * 16 + lm;
            for (int r = 0; r < 4; ++r) {
                const float hv = tanhf(c[nt][r]);
                const int b = bq + r;
                hdst[(size_t)b * H_ + j] = (_Float16)hv;
                if (layer == 0) {
                    xh1[((size_t)t * B_ + b) * 1024 + d * 512 + j] = (_Float16)hv;
                } else {
                    dout[((size_t)b * T_ + t) * 1024 + d * 512 + j] = hv;
                }
                if (s == T_ - 1) {
                    dout[16777216ull + ((size_t)(layer * 2 + d) * B_ + b) * 512 + j] = hv;
                }
            }
        }

        // release my slice, then barrier across the 16 blocks of this dir.
        // __threadfence() = agent-scope fence (release side before flag store,
        // acquire side after flag spin) — required across non-coherent XCD L2s.
        __threadfence();
        __syncthreads();
        if (tid == 0)
            __hip_atomic_store(&fl[g], s + 1, __ATOMIC_RELAXED, __HIP_MEMORY_SCOPE_AGENT);
        if (l < 16) {
            while (__hip_atomic_load(&fl[l], __ATOMIC_RELAXED, __HIP_MEMORY_SCOPE_AGENT) < s + 1) {}
        }
        __threadfence();
        __syncthreads();
    }
}

// ---------------------------------------------------------------------------
extern "C" void kernel_launch(void* const* d_in, const int* in_sizes, int n_in,
                              void* d_out, int out_size, void* d_ws, size_t ws_size,
                              hipStream_t stream)
{
    const float* xs   = (const float*)d_in[0];
    const float* wih0 = (const float*)d_in[1];
    const float* whh0 = (const float*)d_in[2];
    const float* b0   = (const float*)d_in[3];
    const float* wih1 = (const float*)d_in[4];
    const float* whh1 = (const float*)d_in[5];
    const float* b1   = (const float*)d_in[6];

    char* ws = (char*)d_ws;
    _Float16* pre  = (_Float16*)(ws + OFF_PRE);
    _Float16* xh1  = (_Float16*)(ws + OFF_XH1);
    _Float16* x0h  = (_Float16*)(ws + OFF_X0H);
    _Float16* w0h  = (_Float16*)(ws + OFF_W0H);
    _Float16* w1h  = (_Float16*)(ws + OFF_W1H);
    _Float16* whh  = (_Float16*)(ws + OFF_WHH);
    float*    bsum = (float*)(ws + OFF_BS);
    _Float16* hbuf = (_Float16*)(ws + OFF_HBUF);
    int*      flags= (int*)(ws + OFF_FLAGS);
    float*    out  = (float*)d_out;

    // zero h-state double buffers + barrier flags (ws is poisoned 0xAA)
    (void)hipMemsetAsync(ws + OFF_HBUF, 0, ZERO_SIZE, stream);

    prep_kernel<<<2048, 256, 0, stream>>>(xs, wih0, whh0, b0, wih1, whh1, b1,
                                          x0h, w0h, w1h, whh, bsum);

    // layer 0
    gemm_kernel<<<dim3(256, 8, 2), 256, 0, stream>>>(x0h, w0h, bsum, pre, 256);
    rnn_kernel<<<32, 128, 0, stream>>>(pre, whh, hbuf, flags, xh1, out, 0);

    // layer 1
    gemm_kernel<<<dim3(256, 8, 2), 256, 0, stream>>>(xh1, w1h, bsum + 1024, pre, 1024);
    rnn_kernel<<<32, 128, 0, stream>>>(pre, whh + 2 * 512 * 512,
                                       hbuf + 2 * 2 * B_ * H_, flags + 32,
                                       xh1, out, 1);
}